// Round 1
// baseline (169.926 us; speedup 1.0000x reference)
//
#include <hip/hip_runtime.h>
#include <stdint.h>

// ---------------------------------------------------------------------------
// Fused MHA block: qkv proj -> flash attention -> out proj.
// Inputs fp32, output fp32; bf16 MFMA compute, fp32 accum.
// B=4 N=2048 C=512 H=8 D=64 fixed.
// R18: attn_fused reworked to 64 q-rows/wave (2 waves x 64q = 128q/block,
// 128-thread blocks). Each LDS K/V fragment read feeds TWO MFMAs (qt=0,1),
// halving per-CU LDS read traffic (the measured bottleneck: 3.1K cyc/iter
// LDS vs 2.1K MFMA). Grid/XCD remap/LDS layout/pi-permuted PV unchanged.
// ---------------------------------------------------------------------------

typedef short bf16x8 __attribute__((ext_vector_type(8)));   // 8 bf16 = 4 VGPRs
typedef float f32x2  __attribute__((ext_vector_type(2)));
typedef float f32x4  __attribute__((ext_vector_type(4)));
typedef float f32x16 __attribute__((ext_vector_type(16)));
typedef unsigned int u32x4 __attribute__((ext_vector_type(4)));

__device__ __forceinline__ unsigned short f2bf(float f) {
    unsigned int u = __builtin_bit_cast(unsigned int, f);
    u += 0x7fffu + ((u >> 16) & 1u);
    return (unsigned short)(u >> 16);
}
__device__ __forceinline__ unsigned int pk2(float a, float b) {
    return (unsigned int)f2bf(a) | ((unsigned int)f2bf(b) << 16);
}
__device__ __forceinline__ float fexp2(float x) {
    return __builtin_amdgcn_exp2f(x);    // bare v_exp_f32
}
__device__ __forceinline__ bf16x8 ld8_f32(const float* __restrict__ p) {
    float4 f0 = *(const float4*)p;
    float4 f1 = *(const float4*)(p + 4);
    u32x4 u = {pk2(f0.x, f0.y), pk2(f0.z, f0.w), pk2(f1.x, f1.y), pk2(f1.z, f1.w)};
    return __builtin_bit_cast(bf16x8, u);
}
__device__ __forceinline__ void async16(const void* g, void* l) {
    __builtin_amdgcn_global_load_lds(
        (const __attribute__((address_space(1))) unsigned int*)g,
        (__attribute__((address_space(3))) unsigned int*)l,
        16, 0, 0);
}

#define MFMA16(a, b, c) __builtin_amdgcn_mfma_f32_16x16x32_bf16((a), (b), (c), 0, 0, 0)
#define MFMA32(a, b, c) __builtin_amdgcn_mfma_f32_32x32x16_bf16((a), (b), (c), 0, 0, 0)

// ---------------------------------------------------------------------------
// fp32 -> bf16 bulk convert: x, qkv_w, proj_w in one pass.
// ---------------------------------------------------------------------------
__global__ void cvt_bf16(const float* __restrict__ x,
                         const float* __restrict__ w,
                         const float* __restrict__ w2,
                         unsigned short* __restrict__ xb,
                         unsigned short* __restrict__ wb,
                         unsigned short* __restrict__ wb2)
{
    const int G = 524288 + 98304 + 32768;
    for (int idx = blockIdx.x * 256 + threadIdx.x; idx < G; idx += gridDim.x * 256) {
        if (idx < 524288)
            *(bf16x8*)(xb + (size_t)idx * 8) = ld8_f32(x + (size_t)idx * 8);
        else if (idx < 524288 + 98304) {
            int j = idx - 524288;
            *(bf16x8*)(wb + (size_t)j * 8) = ld8_f32(w + (size_t)j * 8);
        } else {
            int j = idx - 524288 - 98304;
            *(bf16x8*)(wb2 + (size_t)j * 8) = ld8_f32(w2 + (size_t)j * 8);
        }
    }
}

// ---------------------------------------------------------------------------
// QKV GEMM: 128x128 tile / 4 waves; BK=32; dual DMA staging; 4 blocks/CU.
// XCD remap: XCD k owns A-rows [8k,8k+8) x all 12 col-tiles.
// ---------------------------------------------------------------------------
__global__ __launch_bounds__(256, 4)
void gemm_qkv(const unsigned short* __restrict__ A,
              const unsigned short* __restrict__ B,
              const float* __restrict__ bias,
              unsigned short* __restrict__ out0,
              unsigned short* __restrict__ out1,
              unsigned short* __restrict__ out2,
              int K)
{
    __shared__ unsigned short sA[128 * 32];
    __shared__ unsigned short sB[128 * 32];

    const int tid  = threadIdx.x;
    const int wave = tid >> 6, lane = tid & 63;
    const int l = lane & 15, q16 = lane >> 4;
    const int wm = wave >> 1, wn = wave & 1;
    const int bid = blockIdx.x;                  // 0..767
    const int slot = bid >> 3;                   // 0..95
    const int m0 = ((bid & 7) * 8 + slot / 12) * 128;
    const int n0 = (slot % 12) * 128;

    f32x4 acc[4][4];
#pragma unroll
    for (int i = 0; i < 4; ++i)
#pragma unroll
        for (int j = 0; j < 4; ++j)
            acc[i][j] = (f32x4){0.f, 0.f, 0.f, 0.f};

    for (int k0 = 0; k0 < K; k0 += 32) {
#pragma unroll
        for (int call = 0; call < 2; ++call) {
            int L = call * 256 + tid;
            int r = L >> 2, c = L & 3;
            async16(A + (size_t)(m0 + r) * K + k0 + c * 8, sA + L * 8);
            async16(B + (size_t)(n0 + r) * K + k0 + c * 8, sB + L * 8);
        }
        __syncthreads();

        bf16x8 af[4], bfr[4];
#pragma unroll
        for (int i = 0; i < 4; ++i)
            af[i] = *(const bf16x8*)(sA + ((wm * 64 + i * 16 + l) * 4 + q16) * 8);
#pragma unroll
        for (int j = 0; j < 4; ++j)
            bfr[j] = *(const bf16x8*)(sB + ((wn * 64 + j * 16 + l) * 4 + q16) * 8);
#pragma unroll
        for (int i = 0; i < 4; ++i)
#pragma unroll
            for (int j = 0; j < 4; ++j)
                acc[i][j] = MFMA16(af[i], bfr[j], acc[i][j]);
        __syncthreads();
    }

    const float lscale = 0.18033688f;  // D^-0.5 * log2(e), folded into q
#pragma unroll
    for (int i = 0; i < 4; ++i) {
#pragma unroll
        for (int j = 0; j < 4; ++j) {
            int col = n0 + wn * 64 + j * 16 + l;
            float bv = bias[col];
#pragma unroll
            for (int r = 0; r < 4; ++r) {
                int row = m0 + wm * 64 + i * 16 + q16 * 4 + r;
                float val = acc[i][j][r] + bv;
                int which = col >> 9;            // 0:q 1:k 2:v
                int h = (col >> 6) & 7, d = col & 63;
                int b = row >> 11, n = row & 2047;
                if (which == 0)
                    out0[(size_t)(((b * 8 + h) * 2048) + n) * 64 + d] = f2bf(val * lscale);
                else if (which == 1)
                    out1[(size_t)(((b * 8 + h) * 2048) + n) * 64 + d] = f2bf(val);
                else {
                    // V^T with pi(n): swap bits 2<->3 of n (within 32-blocks)
                    int np = (n & ~12) | ((n & 8) >> 1) | ((n & 4) << 1);
                    out2[(size_t)(((b * 8 + h) * 64) + d) * 2048 + np] = f2bf(val);
                }
            }
        }
    }
}

// ---------------------------------------------------------------------------
// Output GEMM: 64x128 tile / 4 waves; BK=32; 4 blocks/CU. fp32 out + bias.
// XCD remap: XCD k owns rows [16k,16k+16) x 4 col-tiles.
// ---------------------------------------------------------------------------
__global__ __launch_bounds__(256, 4)
void gemm_out(const unsigned short* __restrict__ A,
              const unsigned short* __restrict__ B,
              const float* __restrict__ bias,
              float* __restrict__ outf,
              int K, int N)
{
    __shared__ unsigned short sA[64 * 32];
    __shared__ unsigned short sB[128 * 32];

    const int tid  = threadIdx.x;
    const int wave = tid >> 6, lane = tid & 63;
    const int l = lane & 15, q16 = lane >> 4;
    const int wm = wave >> 1, wn = wave & 1;
    const int bid = blockIdx.x;                  // 0..511
    const int slot = bid >> 3;                   // 0..63
    const int m0 = ((bid & 7) * 16 + (slot >> 2)) * 64;
    const int n0 = (slot & 3) * 128;

    f32x4 acc[2][4];
#pragma unroll
    for (int i = 0; i < 2; ++i)
#pragma unroll
        for (int j = 0; j < 4; ++j)
            acc[i][j] = (f32x4){0.f, 0.f, 0.f, 0.f};

    for (int k0 = 0; k0 < K; k0 += 32) {
        {
            int r = tid >> 2, c = tid & 3;       // A: 256 slots
            async16(A + (size_t)(m0 + r) * K + k0 + c * 8, sA + tid * 8);
        }
#pragma unroll
        for (int call = 0; call < 2; ++call) {   // B: 512 slots
            int L = call * 256 + tid;
            int r = L >> 2, c = L & 3;
            async16(B + (size_t)(n0 + r) * K + k0 + c * 8, sB + L * 8);
        }
        __syncthreads();

        bf16x8 af[2], bfr[4];
#pragma unroll
        for (int i = 0; i < 2; ++i)
            af[i] = *(const bf16x8*)(sA + ((wm * 32 + i * 16 + l) * 4 + q16) * 8);
#pragma unroll
        for (int j = 0; j < 4; ++j)
            bfr[j] = *(const bf16x8*)(sB + ((wn * 64 + j * 16 + l) * 4 + q16) * 8);
#pragma unroll
        for (int i = 0; i < 2; ++i)
#pragma unroll
            for (int j = 0; j < 4; ++j)
                acc[i][j] = MFMA16(af[i], bfr[j], acc[i][j]);
        __syncthreads();
    }

#pragma unroll
    for (int i = 0; i < 2; ++i) {
#pragma unroll
        for (int j = 0; j < 4; ++j) {
            int col = n0 + wn * 64 + j * 16 + l;
            float bv = bias[col];
#pragma unroll
            for (int r = 0; r < 4; ++r) {
                int row = m0 + wm * 32 + i * 16 + q16 * 4 + r;
                outf[(size_t)row * N + col] = acc[i][j][r] + bv;
            }
        }
    }
}

// ---------------------------------------------------------------------------
// Flash attention R18: 128 threads (2 waves), 64 q-rows per wave (qt=0,1).
// Each K/V LDS fragment read feeds 2 MFMAs -> LDS read traffic halved.
// Double-buffered DMA staging, S^T on 32x32x16, static-max softmax,
// swap-free PV via pi-permuted V^T. XCD remap: 4 heads per XCD.
// ---------------------------------------------------------------------------
__global__ __launch_bounds__(128, 1)
void attn_fused(const unsigned short* __restrict__ Q,
                const unsigned short* __restrict__ Km,
                const unsigned short* __restrict__ Vt,
                unsigned short* __restrict__ O)
{
    __shared__ unsigned short sK[2][128 * 64];
    __shared__ unsigned short sVt[2][64 * 128];

    const int tid  = threadIdx.x;
    const int wave = tid >> 6, lane = tid & 63;
    const int l31 = lane & 31, h = lane >> 5;
    const int swz = l31 & 7;
    const int bid = blockIdx.x;                  // 0..511
    const int slot = bid >> 3;                   // 0..63
    const int bh = (bid & 7) * 4 + (slot >> 4);  // 4 heads per XCD
    const int n0 = (slot & 15) * 128;
    const int q0 = n0 + wave * 64;               // this wave: q0..q0+63

    const unsigned short* Kp = Km + (size_t)bh * 2048 * 64;
    const unsigned short* Vp = Vt + (size_t)bh * 64 * 2048;
    const unsigned short* sKf = &sK[0][0];
    const unsigned short* sVf = &sVt[0][0];

    int ka[4], va[2][2];
#pragma unroll
    for (int ks = 0; ks < 4; ++ks)
        ka[ks] = l31 * 64 + ((ks * 2 + h) ^ swz) * 8;
#pragma unroll
    for (int m1 = 0; m1 < 2; ++m1)
#pragma unroll
        for (int ks2 = 0; ks2 < 2; ++ks2)
            va[m1][ks2] = l31 * 128 + ((m1 * 4 + ks2 * 2 + h) ^ swz) * 8;

    // staging: 1024 slots of 8 elems, 128 threads -> 8 calls each for K and V
    int ksrc[8], vsrc[8], dst[8];
#pragma unroll
    for (int c = 0; c < 8; ++c) {
        int s = c * 128 + tid;
        int rk = s >> 3;
        ksrc[c] = rk * 64 + ((s & 7) ^ (rk & 7)) * 8;
        int rv = s >> 4;
        vsrc[c] = rv * 2048 + ((s & 15) ^ (rv & 7)) * 8;
        dst[c] = s * 8;
    }

    bf16x8 qf[2][4];
#pragma unroll
    for (int qt = 0; qt < 2; ++qt)
#pragma unroll
        for (int ks = 0; ks < 4; ++ks)
            qf[qt][ks] = *(const bf16x8*)(Q + (size_t)(bh * 2048 + q0 + qt * 32 + l31) * 64
                                          + ks * 16 + h * 8);

    f32x16 oacc[2][2];
#pragma unroll
    for (int qt = 0; qt < 2; ++qt)
#pragma unroll
        for (int dt = 0; dt < 2; ++dt)
#pragma unroll
            for (int e = 0; e < 16; ++e) oacc[qt][dt][e] = 0.f;
    f32x16 Zv;
#pragma unroll
    for (int e = 0; e < 16; ++e) Zv[e] = 0.f;
    f32x2 l2[2];
    l2[0] = (f32x2){0.f, 0.f};
    l2[1] = (f32x2){0.f, 0.f};

#pragma unroll
    for (int c = 0; c < 8; ++c) {
        async16(Kp + ksrc[c], (void*)(sKf + dst[c]));
        async16(Vp + vsrc[c], (void*)(sVf + dst[c]));
    }
    __syncthreads();

    for (int it = 0; it < 16; ++it) {
        const int nb = ((it + 1) & 1) * 8192;
        if (it < 15) {
            int kv = (it + 1) * 128;
#pragma unroll
            for (int c = 0; c < 8; ++c)
                async16(Kp + (size_t)kv * 64 + ksrc[c], (void*)(sKf + nb + dst[c]));
        }

        // QK^T: 16 K-fragment reads, 32 MFMAs (each kf feeds both q-subtiles)
        f32x16 sacc[2][4];
#pragma unroll
        for (int mt = 0; mt < 4; ++mt) {
            bf16x8 kf0 = *(const bf16x8*)(sKf + ka[0] + mt * 2048);
            sacc[0][mt] = MFMA32(kf0, qf[0][0], Zv);
            sacc[1][mt] = MFMA32(kf0, qf[1][0], Zv);
#pragma unroll
            for (int ks = 1; ks < 4; ++ks) {
                bf16x8 kf = *(const bf16x8*)(sKf + ka[ks] + mt * 2048);
                sacc[0][mt] = MFMA32(kf, qf[0][ks], sacc[0][mt]);
                sacc[1][mt] = MFMA32(kf, qf[1][ks], sacc[1][mt]);
            }
        }

        if (it < 15) {
            int kv = (it + 1) * 128;
#pragma unroll
            for (int c = 0; c < 8; ++c)
                async16(Vp + (size_t)kv + vsrc[c], (void*)(sVf + nb + dst[c]));
        }

        // softmax + PV fused per kv-subtile mt: exp VALU of mt+1 overlaps
        // PV MFMAs of mt. Each vf read feeds both q-subtiles.
#pragma unroll
        for (int mt = 0; mt < 4; ++mt) {
            unsigned int pk[2][4][2];
#pragma unroll
            for (int qt = 0; qt < 2; ++qt) {
#pragma unroll
                for (int g = 0; g < 4; ++g) {
                    float p0 = fexp2(sacc[qt][mt][4 * g + 0]);
                    float p1 = fexp2(sacc[qt][mt][4 * g + 1]);
                    float p2 = fexp2(sacc[qt][mt][4 * g + 2]);
                    float p3 = fexp2(sacc[qt][mt][4 * g + 3]);
                    l2[qt] += (f32x2){p0, p1};
                    l2[qt] += (f32x2){p2, p3};
                    pk[qt][g][0] = __builtin_amdgcn_perm(
                        __builtin_bit_cast(unsigned int, p1),
                        __builtin_bit_cast(unsigned int, p0), 0x07060302u);
                    pk[qt][g][1] = __builtin_amdgcn_perm(
                        __builtin_bit_cast(unsigned int, p3),
                        __builtin_bit_cast(unsigned int, p2), 0x07060302u);
                }
            }
#pragma unroll
            for (int ks2 = 0; ks2 < 2; ++ks2) {
                u32x4 bu0, bu1;
                bu0[0] = pk[0][2 * ks2][0];
                bu0[1] = pk[0][2 * ks2][1];
                bu0[2] = pk[0][2 * ks2 + 1][0];
                bu0[3] = pk[0][2 * ks2 + 1][1];
                bu1[0] = pk[1][2 * ks2][0];
                bu1[1] = pk[1][2 * ks2][1];
                bu1[2] = pk[1][2 * ks2 + 1][0];
                bu1[3] = pk[1][2 * ks2 + 1][1];
                bf16x8 bf0 = __builtin_bit_cast(bf16x8, bu0);
                bf16x8 bf1 = __builtin_bit_cast(bf16x8, bu1);
#pragma unroll
                for (int dt = 0; dt < 2; ++dt) {
                    bf16x8 vf = *(const bf16x8*)(sVf + va[mt & 1][ks2]
                                                 + (mt >> 1) * 64 + dt * 4096);
                    oacc[0][dt] = MFMA32(vf, bf0, oacc[0][dt]);
                    oacc[1][dt] = MFMA32(vf, bf1, oacc[1][dt]);
                }
            }
        }

#pragma unroll
        for (int ks = 0; ks < 4; ++ks) ka[ks] ^= 8192;
        va[0][0] ^= 8192; va[0][1] ^= 8192; va[1][0] ^= 8192; va[1][1] ^= 8192;
        __syncthreads();
    }

    const int b = bh >> 3, hh = bh & 7;
#pragma unroll
    for (int qt = 0; qt < 2; ++qt) {
        float l_run = l2[qt][0] + l2[qt][1];
        l_run += __shfl_xor(l_run, 32);
        float inv = 1.f / fmaxf(l_run, 1e-20f);
        unsigned short* obase = O + ((size_t)(b * 2048 + q0 + qt * 32 + l31)) * 512 + hh * 64;
#pragma unroll
        for (int dt = 0; dt < 2; ++dt)
#pragma unroll
            for (int g = 0; g < 4; ++g) {
                int d = dt * 32 + 8 * g + 4 * h;
                unsigned int w0 = pk2(oacc[qt][dt][4 * g + 0] * inv,
                                      oacc[qt][dt][4 * g + 1] * inv);
                unsigned int w1 = pk2(oacc[qt][dt][4 * g + 2] * inv,
                                      oacc[qt][dt][4 * g + 3] * inv);
                uint2 w = {w0, w1};
                *(uint2*)(obase + d) = w;
            }
    }
}

// ---------------------------------------------------------------------------
extern "C" void kernel_launch(void* const* d_in, const int* in_sizes, int n_in,
                              void* d_out, int out_size, void* d_ws, size_t ws_size,
                              hipStream_t stream)
{
    const float* x      = (const float*)d_in[0];  // [4,2048,512]
    const float* qkv_w  = (const float*)d_in[1];  // [1536,512]
    const float* qkv_b  = (const float*)d_in[2];  // [1536]
    const float* proj_w = (const float*)d_in[3];  // [512,512]
    const float* proj_b = (const float*)d_in[4];  // [512]

    const size_t PER = 4u * 8u * 2048u * 64u;     // 4,194,304 elems (8 MB bf16)
    unsigned short* q_ws  = (unsigned short*)d_ws;
    unsigned short* k_ws  = q_ws  + PER;
    unsigned short* vt_ws = k_ws  + PER;
    unsigned short* ao_ws = vt_ws + PER;
    unsigned short* wb2   = ao_ws + PER;          // proj_w bf16 (0.5 MB)

    // bf16 scratch inside d_out (16 MB; dead until final GEMM overwrites it)
    unsigned short* xb = (unsigned short*)d_out;          // 8 MB
    unsigned short* wb = xb + PER;                        // 1.5 MB

    // 0) bulk fp32->bf16 of x, qkv_w, proj_w (one launch)
    cvt_bf16<<<dim3(640), 256, 0, stream>>>(x, qkv_w, proj_w, xb, wb, wb2);
    // 1) QKV projection: M=8192, N=1536, K=512 (XCD-remapped)
    gemm_qkv<<<dim3(768), 256, 0, stream>>>(xb, wb, qkv_b, q_ws, k_ws, vt_ws, 512);
    // 2) Flash attention: 512 blocks x 128 threads, 64 q/wave (XCD-remapped)
    attn_fused<<<dim3(512), 128, 0, stream>>>(q_ws, k_ws, vt_ws, ao_ws);
    // 3) Output projection: M=8192, N=512, K=512 (XCD-remapped)
    gemm_out<<<dim3(512), 256, 0, stream>>>(ao_ws, wb2, proj_b, (float*)d_out, 512, 512);
}

// Round 2
// 155.955 us; speedup vs baseline: 1.0896x; 1.0896x over previous
//
#include <hip/hip_runtime.h>
#include <stdint.h>

// ---------------------------------------------------------------------------
// Fused MHA block: qkv proj -> flash attention -> out proj.
// Inputs fp32, output fp32; bf16 MFMA compute, fp32 accum.
// B=4 N=2048 C=512 H=8 D=64 fixed.
// R19: attn_fused = 256 threads / 4 waves, wave (qh,kh) computes 64 q-rows
// x 64 kv-cols of each 128-kv tile. Keeps R18's halved LDS read traffic
// (each K/V fragment feeds 2 MFMAs) while restoring R14's 2 waves/SIMD
// occupancy (R18's 1 wave/SIMD exposed all lgkmcnt/barrier stalls: 63us).
// kv-half partials (oacc, l2) merged additively via LDS epilogue (static-max
// softmax -> merge is pure addition). pi-permuted V^T PV path unchanged.
// ---------------------------------------------------------------------------

typedef short bf16x8 __attribute__((ext_vector_type(8)));   // 8 bf16 = 4 VGPRs
typedef float f32x2  __attribute__((ext_vector_type(2)));
typedef float f32x4  __attribute__((ext_vector_type(4)));
typedef float f32x16 __attribute__((ext_vector_type(16)));
typedef unsigned int u32x4 __attribute__((ext_vector_type(4)));

__device__ __forceinline__ unsigned short f2bf(float f) {
    unsigned int u = __builtin_bit_cast(unsigned int, f);
    u += 0x7fffu + ((u >> 16) & 1u);
    return (unsigned short)(u >> 16);
}
__device__ __forceinline__ unsigned int pk2(float a, float b) {
    return (unsigned int)f2bf(a) | ((unsigned int)f2bf(b) << 16);
}
__device__ __forceinline__ float fexp2(float x) {
    return __builtin_amdgcn_exp2f(x);    // bare v_exp_f32
}
__device__ __forceinline__ bf16x8 ld8_f32(const float* __restrict__ p) {
    float4 f0 = *(const float4*)p;
    float4 f1 = *(const float4*)(p + 4);
    u32x4 u = {pk2(f0.x, f0.y), pk2(f0.z, f0.w), pk2(f1.x, f1.y), pk2(f1.z, f1.w)};
    return __builtin_bit_cast(bf16x8, u);
}
__device__ __forceinline__ void async16(const void* g, void* l) {
    __builtin_amdgcn_global_load_lds(
        (const __attribute__((address_space(1))) unsigned int*)g,
        (__attribute__((address_space(3))) unsigned int*)l,
        16, 0, 0);
}

#define MFMA16(a, b, c) __builtin_amdgcn_mfma_f32_16x16x32_bf16((a), (b), (c), 0, 0, 0)
#define MFMA32(a, b, c) __builtin_amdgcn_mfma_f32_32x32x16_bf16((a), (b), (c), 0, 0, 0)

// ---------------------------------------------------------------------------
// fp32 -> bf16 bulk convert: x, qkv_w, proj_w in one pass.
// ---------------------------------------------------------------------------
__global__ void cvt_bf16(const float* __restrict__ x,
                         const float* __restrict__ w,
                         const float* __restrict__ w2,
                         unsigned short* __restrict__ xb,
                         unsigned short* __restrict__ wb,
                         unsigned short* __restrict__ wb2)
{
    const int G = 524288 + 98304 + 32768;
    for (int idx = blockIdx.x * 256 + threadIdx.x; idx < G; idx += gridDim.x * 256) {
        if (idx < 524288)
            *(bf16x8*)(xb + (size_t)idx * 8) = ld8_f32(x + (size_t)idx * 8);
        else if (idx < 524288 + 98304) {
            int j = idx - 524288;
            *(bf16x8*)(wb + (size_t)j * 8) = ld8_f32(w + (size_t)j * 8);
        } else {
            int j = idx - 524288 - 98304;
            *(bf16x8*)(wb2 + (size_t)j * 8) = ld8_f32(w2 + (size_t)j * 8);
        }
    }
}

// ---------------------------------------------------------------------------
// QKV GEMM: 128x128 tile / 4 waves; BK=32; dual DMA staging; 4 blocks/CU.
// XCD remap: XCD k owns A-rows [8k,8k+8) x all 12 col-tiles.
// ---------------------------------------------------------------------------
__global__ __launch_bounds__(256, 4)
void gemm_qkv(const unsigned short* __restrict__ A,
              const unsigned short* __restrict__ B,
              const float* __restrict__ bias,
              unsigned short* __restrict__ out0,
              unsigned short* __restrict__ out1,
              unsigned short* __restrict__ out2,
              int K)
{
    __shared__ unsigned short sA[128 * 32];
    __shared__ unsigned short sB[128 * 32];

    const int tid  = threadIdx.x;
    const int wave = tid >> 6, lane = tid & 63;
    const int l = lane & 15, q16 = lane >> 4;
    const int wm = wave >> 1, wn = wave & 1;
    const int bid = blockIdx.x;                  // 0..767
    const int slot = bid >> 3;                   // 0..95
    const int m0 = ((bid & 7) * 8 + slot / 12) * 128;
    const int n0 = (slot % 12) * 128;

    f32x4 acc[4][4];
#pragma unroll
    for (int i = 0; i < 4; ++i)
#pragma unroll
        for (int j = 0; j < 4; ++j)
            acc[i][j] = (f32x4){0.f, 0.f, 0.f, 0.f};

    for (int k0 = 0; k0 < K; k0 += 32) {
#pragma unroll
        for (int call = 0; call < 2; ++call) {
            int L = call * 256 + tid;
            int r = L >> 2, c = L & 3;
            async16(A + (size_t)(m0 + r) * K + k0 + c * 8, sA + L * 8);
            async16(B + (size_t)(n0 + r) * K + k0 + c * 8, sB + L * 8);
        }
        __syncthreads();

        bf16x8 af[4], bfr[4];
#pragma unroll
        for (int i = 0; i < 4; ++i)
            af[i] = *(const bf16x8*)(sA + ((wm * 64 + i * 16 + l) * 4 + q16) * 8);
#pragma unroll
        for (int j = 0; j < 4; ++j)
            bfr[j] = *(const bf16x8*)(sB + ((wn * 64 + j * 16 + l) * 4 + q16) * 8);
#pragma unroll
        for (int i = 0; i < 4; ++i)
#pragma unroll
            for (int j = 0; j < 4; ++j)
                acc[i][j] = MFMA16(af[i], bfr[j], acc[i][j]);
        __syncthreads();
    }

    const float lscale = 0.18033688f;  // D^-0.5 * log2(e), folded into q
#pragma unroll
    for (int i = 0; i < 4; ++i) {
#pragma unroll
        for (int j = 0; j < 4; ++j) {
            int col = n0 + wn * 64 + j * 16 + l;
            float bv = bias[col];
#pragma unroll
            for (int r = 0; r < 4; ++r) {
                int row = m0 + wm * 64 + i * 16 + q16 * 4 + r;
                float val = acc[i][j][r] + bv;
                int which = col >> 9;            // 0:q 1:k 2:v
                int h = (col >> 6) & 7, d = col & 63;
                int b = row >> 11, n = row & 2047;
                if (which == 0)
                    out0[(size_t)(((b * 8 + h) * 2048) + n) * 64 + d] = f2bf(val * lscale);
                else if (which == 1)
                    out1[(size_t)(((b * 8 + h) * 2048) + n) * 64 + d] = f2bf(val);
                else {
                    // V^T with pi(n): swap bits 2<->3 of n (within 32-blocks)
                    int np = (n & ~12) | ((n & 8) >> 1) | ((n & 4) << 1);
                    out2[(size_t)(((b * 8 + h) * 64) + d) * 2048 + np] = f2bf(val);
                }
            }
        }
    }
}

// ---------------------------------------------------------------------------
// Output GEMM: 64x128 tile / 4 waves; BK=32; 4 blocks/CU. fp32 out + bias.
// XCD remap: XCD k owns rows [16k,16k+16) x 4 col-tiles.
// ---------------------------------------------------------------------------
__global__ __launch_bounds__(256, 4)
void gemm_out(const unsigned short* __restrict__ A,
              const unsigned short* __restrict__ B,
              const float* __restrict__ bias,
              float* __restrict__ outf,
              int K, int N)
{
    __shared__ unsigned short sA[64 * 32];
    __shared__ unsigned short sB[128 * 32];

    const int tid  = threadIdx.x;
    const int wave = tid >> 6, lane = tid & 63;
    const int l = lane & 15, q16 = lane >> 4;
    const int wm = wave >> 1, wn = wave & 1;
    const int bid = blockIdx.x;                  // 0..511
    const int slot = bid >> 3;                   // 0..63
    const int m0 = ((bid & 7) * 16 + (slot >> 2)) * 64;
    const int n0 = (slot & 3) * 128;

    f32x4 acc[2][4];
#pragma unroll
    for (int i = 0; i < 2; ++i)
#pragma unroll
        for (int j = 0; j < 4; ++j)
            acc[i][j] = (f32x4){0.f, 0.f, 0.f, 0.f};

    for (int k0 = 0; k0 < K; k0 += 32) {
        {
            int r = tid >> 2, c = tid & 3;       // A: 256 slots
            async16(A + (size_t)(m0 + r) * K + k0 + c * 8, sA + tid * 8);
        }
#pragma unroll
        for (int call = 0; call < 2; ++call) {   // B: 512 slots
            int L = call * 256 + tid;
            int r = L >> 2, c = L & 3;
            async16(B + (size_t)(n0 + r) * K + k0 + c * 8, sB + L * 8);
        }
        __syncthreads();

        bf16x8 af[2], bfr[4];
#pragma unroll
        for (int i = 0; i < 2; ++i)
            af[i] = *(const bf16x8*)(sA + ((wm * 32 + i * 16 + l) * 4 + q16) * 8);
#pragma unroll
        for (int j = 0; j < 4; ++j)
            bfr[j] = *(const bf16x8*)(sB + ((wn * 64 + j * 16 + l) * 4 + q16) * 8);
#pragma unroll
        for (int i = 0; i < 2; ++i)
#pragma unroll
            for (int j = 0; j < 4; ++j)
                acc[i][j] = MFMA16(af[i], bfr[j], acc[i][j]);
        __syncthreads();
    }

#pragma unroll
    for (int i = 0; i < 2; ++i) {
#pragma unroll
        for (int j = 0; j < 4; ++j) {
            int col = n0 + wn * 64 + j * 16 + l;
            float bv = bias[col];
#pragma unroll
            for (int r = 0; r < 4; ++r) {
                int row = m0 + wm * 32 + i * 16 + q16 * 4 + r;
                outf[(size_t)row * N + col] = acc[i][j][r] + bv;
            }
        }
    }
}

// ---------------------------------------------------------------------------
// Flash attention R19: 256 threads / 4 waves; wave (qh,kh): q-rows qh*64..+63
// vs kv-half kh*64..+63 of each 128-kv tile. 16 ds_read_b128 feed 32 MFMA32
// per wave per iter (1:2 ratio); 2 blocks/CU -> 2 waves/SIMD. kv-half
// partials merged additively via LDS epilogue.
// ---------------------------------------------------------------------------
__global__ __launch_bounds__(256, 2)
void attn_fused(const unsigned short* __restrict__ Q,
                const unsigned short* __restrict__ Km,
                const unsigned short* __restrict__ Vt,
                unsigned short* __restrict__ O)
{
    __shared__ unsigned short sK[2][128 * 64];
    __shared__ unsigned short sVt[2][64 * 128];

    const int tid  = threadIdx.x;
    const int wave = tid >> 6, lane = tid & 63;
    const int l31 = lane & 31, h = lane >> 5;
    const int swz = l31 & 7;
    const int qh = wave & 1, kh = wave >> 1;
    const int bid = blockIdx.x;                  // 0..511
    const int slot = bid >> 3;                   // 0..63
    const int bh = (bid & 7) * 4 + (slot >> 4);  // 4 heads per XCD
    const int n0 = (slot & 15) * 128;
    const int q0 = n0 + qh * 64;                 // this wave: q0..q0+63

    const unsigned short* Kp = Km + (size_t)bh * 2048 * 64;
    const unsigned short* Vp = Vt + (size_t)bh * 64 * 2048;
    const unsigned short* sKf = &sK[0][0];
    const unsigned short* sVf = &sVt[0][0];

    // K fragment addrs: row = kh*64 + mt*32 + l31 (row&7 == l31&7 == swz),
    // chunk = (ks*2+h)^swz. mt*2048 added at use.
    int ka[4], va[2][2];
#pragma unroll
    for (int ks = 0; ks < 4; ++ks)
        ka[ks] = (kh * 64 + l31) * 64 + ((ks * 2 + h) ^ swz) * 8;
    // V^T fragment addrs: row = d = l31 (+dt*32 at use), kv chunk
    // kh*8 + (m1*4+ks2*2+h): low-3-bit XOR swizzle, +kh*64 raw col offset.
#pragma unroll
    for (int m1 = 0; m1 < 2; ++m1)
#pragma unroll
        for (int ks2 = 0; ks2 < 2; ++ks2)
            va[m1][ks2] = l31 * 128 + ((m1 * 4 + ks2 * 2 + h) ^ swz) * 8 + kh * 64;

    // staging: 1024 slots of 8 elems, 256 threads -> 4 calls each for K and V
    int ksrc[4], vsrc[4], dst[4];
#pragma unroll
    for (int c = 0; c < 4; ++c) {
        int s = wave * 256 + c * 64 + lane;
        int rk = s >> 3;
        ksrc[c] = rk * 64 + ((s & 7) ^ (rk & 7)) * 8;
        int rv = s >> 4;
        vsrc[c] = rv * 2048 + ((s & 15) ^ (rv & 7)) * 8;
        dst[c] = s * 8;
    }

    bf16x8 qf[2][4];
#pragma unroll
    for (int qt = 0; qt < 2; ++qt)
#pragma unroll
        for (int ks = 0; ks < 4; ++ks)
            qf[qt][ks] = *(const bf16x8*)(Q + (size_t)(bh * 2048 + q0 + qt * 32 + l31) * 64
                                          + ks * 16 + h * 8);

    f32x16 oacc[2][2];
#pragma unroll
    for (int qt = 0; qt < 2; ++qt)
#pragma unroll
        for (int dt = 0; dt < 2; ++dt)
#pragma unroll
            for (int e = 0; e < 16; ++e) oacc[qt][dt][e] = 0.f;
    f32x16 Zv;
#pragma unroll
    for (int e = 0; e < 16; ++e) Zv[e] = 0.f;
    f32x2 l2[2];
    l2[0] = (f32x2){0.f, 0.f};
    l2[1] = (f32x2){0.f, 0.f};

#pragma unroll
    for (int c = 0; c < 4; ++c) {
        async16(Kp + ksrc[c], (void*)(sKf + dst[c]));
        async16(Vp + vsrc[c], (void*)(sVf + dst[c]));
    }
    __syncthreads();

    for (int it = 0; it < 16; ++it) {
        const int nb = ((it + 1) & 1) * 8192;
        if (it < 15) {
            int kv = (it + 1) * 128;
#pragma unroll
            for (int c = 0; c < 4; ++c)
                async16(Kp + (size_t)kv * 64 + ksrc[c], (void*)(sKf + nb + dst[c]));
        }

        // QK^T for this wave's kv-half: 8 K reads feed 16 MFMAs.
        f32x16 sacc[2][2];
#pragma unroll
        for (int mt = 0; mt < 2; ++mt) {
            bf16x8 kf0 = *(const bf16x8*)(sKf + ka[0] + mt * 2048);
            sacc[0][mt] = MFMA32(kf0, qf[0][0], Zv);
            sacc[1][mt] = MFMA32(kf0, qf[1][0], Zv);
#pragma unroll
            for (int ks = 1; ks < 4; ++ks) {
                bf16x8 kf = *(const bf16x8*)(sKf + ka[ks] + mt * 2048);
                sacc[0][mt] = MFMA32(kf, qf[0][ks], sacc[0][mt]);
                sacc[1][mt] = MFMA32(kf, qf[1][ks], sacc[1][mt]);
            }
        }

        if (it < 15) {
            int kv = (it + 1) * 128;
#pragma unroll
            for (int c = 0; c < 4; ++c)
                async16(Vp + (size_t)kv + vsrc[c], (void*)(sVf + nb + dst[c]));
        }

        // softmax + PV fused per 32-kv subtile mt; 8 V reads feed 16 MFMAs.
#pragma unroll
        for (int mt = 0; mt < 2; ++mt) {
            unsigned int pk[2][4][2];
#pragma unroll
            for (int qt = 0; qt < 2; ++qt) {
#pragma unroll
                for (int g = 0; g < 4; ++g) {
                    float p0 = fexp2(sacc[qt][mt][4 * g + 0]);
                    float p1 = fexp2(sacc[qt][mt][4 * g + 1]);
                    float p2 = fexp2(sacc[qt][mt][4 * g + 2]);
                    float p3 = fexp2(sacc[qt][mt][4 * g + 3]);
                    l2[qt] += (f32x2){p0, p1};
                    l2[qt] += (f32x2){p2, p3};
                    pk[qt][g][0] = __builtin_amdgcn_perm(
                        __builtin_bit_cast(unsigned int, p1),
                        __builtin_bit_cast(unsigned int, p0), 0x07060302u);
                    pk[qt][g][1] = __builtin_amdgcn_perm(
                        __builtin_bit_cast(unsigned int, p3),
                        __builtin_bit_cast(unsigned int, p2), 0x07060302u);
                }
            }
#pragma unroll
            for (int ks2 = 0; ks2 < 2; ++ks2) {
                u32x4 bu0, bu1;
                bu0[0] = pk[0][2 * ks2][0];
                bu0[1] = pk[0][2 * ks2][1];
                bu0[2] = pk[0][2 * ks2 + 1][0];
                bu0[3] = pk[0][2 * ks2 + 1][1];
                bu1[0] = pk[1][2 * ks2][0];
                bu1[1] = pk[1][2 * ks2][1];
                bu1[2] = pk[1][2 * ks2 + 1][0];
                bu1[3] = pk[1][2 * ks2 + 1][1];
                bf16x8 bf0 = __builtin_bit_cast(bf16x8, bu0);
                bf16x8 bf1 = __builtin_bit_cast(bf16x8, bu1);
#pragma unroll
                for (int dt = 0; dt < 2; ++dt) {
                    bf16x8 vf = *(const bf16x8*)(sVf + va[mt][ks2] + dt * 4096);
                    oacc[0][dt] = MFMA32(vf, bf0, oacc[0][dt]);
                    oacc[1][dt] = MFMA32(vf, bf1, oacc[1][dt]);
                }
            }
        }

#pragma unroll
        for (int ks = 0; ks < 4; ++ks) ka[ks] ^= 8192;
        va[0][0] ^= 8192; va[0][1] ^= 8192; va[1][0] ^= 8192; va[1][1] ^= 8192;
        __syncthreads();
    }

    // ---- kv-half merge epilogue (loop exits right after __syncthreads) ----
    // kh=1 waves park partials in dead LDS; kh=0 waves add and write O.
    float* sf = (float*)&sK[0][0];   // 32 KB: oacc partials
    float* sl = (float*)&sVt[0][0];  // 2 KB: l2 partials
    if (kh == 1) {
        const int base = (qh * 64 + lane) * 64;
#pragma unroll
        for (int qt = 0; qt < 2; ++qt)
#pragma unroll
            for (int dt = 0; dt < 2; ++dt) {
                int chunk = (qt * 2 + dt) ^ (lane & 3);   // bank de-phase
                *(f32x16*)(sf + base + chunk * 16) = oacc[qt][dt];
            }
        *(f32x2*)(sl + (qh * 64 + lane) * 4 + 0) = l2[0];
        *(f32x2*)(sl + (qh * 64 + lane) * 4 + 2) = l2[1];
    }
    __syncthreads();
    if (kh == 0) {
        const int base = (qh * 64 + lane) * 64;
#pragma unroll
        for (int qt = 0; qt < 2; ++qt)
#pragma unroll
            for (int dt = 0; dt < 2; ++dt) {
                int chunk = (qt * 2 + dt) ^ (lane & 3);
                f32x16 part = *(const f32x16*)(sf + base + chunk * 16);
#pragma unroll
                for (int e = 0; e < 16; ++e) oacc[qt][dt][e] += part[e];
            }
        l2[0] += *(const f32x2*)(sl + (qh * 64 + lane) * 4 + 0);
        l2[1] += *(const f32x2*)(sl + (qh * 64 + lane) * 4 + 2);

        const int b = bh >> 3, hh = bh & 7;
#pragma unroll
        for (int qt = 0; qt < 2; ++qt) {
            float l_run = l2[qt][0] + l2[qt][1];
            l_run += __shfl_xor(l_run, 32);
            float inv = 1.f / fmaxf(l_run, 1e-20f);
            unsigned short* obase = O + ((size_t)(b * 2048 + q0 + qt * 32 + l31)) * 512 + hh * 64;
#pragma unroll
            for (int dt = 0; dt < 2; ++dt)
#pragma unroll
                for (int g = 0; g < 4; ++g) {
                    int d = dt * 32 + 8 * g + 4 * h;
                    unsigned int w0 = pk2(oacc[qt][dt][4 * g + 0] * inv,
                                          oacc[qt][dt][4 * g + 1] * inv);
                    unsigned int w1 = pk2(oacc[qt][dt][4 * g + 2] * inv,
                                          oacc[qt][dt][4 * g + 3] * inv);
                    uint2 w = {w0, w1};
                    *(uint2*)(obase + d) = w;
                }
        }
    }
}

// ---------------------------------------------------------------------------
extern "C" void kernel_launch(void* const* d_in, const int* in_sizes, int n_in,
                              void* d_out, int out_size, void* d_ws, size_t ws_size,
                              hipStream_t stream)
{
    const float* x      = (const float*)d_in[0];  // [4,2048,512]
    const float* qkv_w  = (const float*)d_in[1];  // [1536,512]
    const float* qkv_b  = (const float*)d_in[2];  // [1536]
    const float* proj_w = (const float*)d_in[3];  // [512,512]
    const float* proj_b = (const float*)d_in[4];  // [512]

    const size_t PER = 4u * 8u * 2048u * 64u;     // 4,194,304 elems (8 MB bf16)
    unsigned short* q_ws  = (unsigned short*)d_ws;
    unsigned short* k_ws  = q_ws  + PER;
    unsigned short* vt_ws = k_ws  + PER;
    unsigned short* ao_ws = vt_ws + PER;
    unsigned short* wb2   = ao_ws + PER;          // proj_w bf16 (0.5 MB)

    // bf16 scratch inside d_out (16 MB; dead until final GEMM overwrites it)
    unsigned short* xb = (unsigned short*)d_out;          // 8 MB
    unsigned short* wb = xb + PER;                        // 1.5 MB

    // 0) bulk fp32->bf16 of x, qkv_w, proj_w (one launch)
    cvt_bf16<<<dim3(640), 256, 0, stream>>>(x, qkv_w, proj_w, xb, wb, wb2);
    // 1) QKV projection: M=8192, N=1536, K=512 (XCD-remapped)
    gemm_qkv<<<dim3(768), 256, 0, stream>>>(xb, wb, qkv_b, q_ws, k_ws, vt_ws, 512);
    // 2) Flash attention: 512 blocks x 256 threads, kv-split waves
    attn_fused<<<dim3(512), 256, 0, stream>>>(q_ws, k_ws, vt_ws, ao_ws);
    // 3) Output projection: M=8192, N=512, K=512 (XCD-remapped)
    gemm_out<<<dim3(512), 256, 0, stream>>>(ao_ws, wb2, proj_b, (float*)d_out, 512, 512);
}